// Round 17
// baseline (143.629 us; speedup 1.0000x reference)
//
#include <hip/hip_runtime.h>
#include <hip/hip_bf16.h>

// MultiLinear: y[b,g,o] = sum_i x[b,g,i] * W[g,o,i] + bias[g,o]
// B=4096, G=16, DIN=512, DOUT=512, fp32 in/out.
// R17 = R15 (best: 72.6us; X-read-once BN=512, B bf16-DMA, chunk-XOR
// conflict-free LDS, counted vmcnt, 1 raw barrier/K-tile) with 16 waves
// (1024 thr) instead of 8: wave-tile 64x64 (2m x 8n), acc 64 AGPR, arch ~60
// -> 4 waves/SIMD (launch_bounds(1024,4), cap 128). Same traffic, same
// schedule; the extra waves/SIMD interleave LDS bursts + MFMA + barrier
// skew that made each K-tile phase ~10k cycles at 2 waves/SIMD.

#define BATCH 4096
#define NGRP  16
#define DIN   512
#define DOUT  512

#define BM 128
#define BN 512
#define BK 64
#define NT (DIN / BK)   // 8 K-tiles

typedef __bf16 bf16x8 __attribute__((ext_vector_type(8)));
typedef float  f32x4  __attribute__((ext_vector_type(4)));
typedef const __attribute__((address_space(1))) void gas_void;
typedef __attribute__((address_space(3))) void las_void;

// ---------- prepass: W fp32 -> bf16 into d_ws ----------
__global__ __launch_bounds__(256)
void wcvt_kernel(const float* __restrict__ W, __bf16* __restrict__ Wb) {
    const int i = (blockIdx.x * 256 + threadIdx.x) * 8;
    f32x4 a = *(const f32x4*)(W + i);
    f32x4 b = *(const f32x4*)(W + i + 4);
    bf16x8 v;
#pragma unroll
    for (int j = 0; j < 4; ++j) { v[j] = (__bf16)a[j]; v[j + 4] = (__bf16)b[j]; }
    *(bf16x8*)(Wb + i) = v;
}

// ---------- main GEMM ----------
__global__ __launch_bounds__(1024, 4)
void MultiLinear_48498770706571_kernel(const float* __restrict__ X,
                                       const __bf16* __restrict__ Wb,
                                       const float* __restrict__ Bias,
                                       float* __restrict__ Y) {
    // 512 blocks / 8 XCDs = 64 consecutive tiles (2 full groups) per XCD.
    const int bid = (blockIdx.x & 7) * 64 + (blockIdx.x >> 3);
    const int g   = bid >> 5;          // 32 m-tiles per group, 1 n-tile
    const int mt  = bid & 31;
    const int bm0 = mt * BM;

    __shared__ __bf16 As[2][BM * BK];    // 32 KB: 128B rows, chunk-swz
    __shared__ __bf16 BsF[2][BN * BK];   // 128 KB: linear, DMA, chunk-swz

    const int tid  = threadIdx.x;
    const int lane = tid & 63;
    const int w    = tid >> 6;        // 0..15
    const int wm   = (w >> 3) * 64;   // {0,64}
    const int wn   = (w & 7) * 64;    // 0..448
    const int l15  = lane & 15;
    const int q    = lane >> 4;       // 0..3

    // A staging: 8 thr/row, 8 floats (32 B) each; 128 rows by 1024 threads.
    const int srow = tid >> 3;        // 0..127
    const int sc   = tid & 7;         // logical 16B-chunk 0..7 within row
    const float* pA = X + (size_t)(bm0 + srow) * (NGRP * DIN) + g * DIN + sc * 8;

    // B DMA geometry: per wave 32 rows; 4 issues of 1 KB (8 rows x 128 B).
    const int drow_l = lane >> 3;     // 0..7 row within instr
    const int dch    = lane & 7;      // 16B chunk within row
    const __bf16* wbase = Wb + (size_t)g * (DOUT * DIN);

    f32x4 ra[2];   // 8 VGPRs in flight (A only; B is DMA)

#define ISSUE_A(k0)                                                        \
    do {                                                                   \
        const f32x4* qa = (const f32x4*)(pA + (k0));                       \
        ra[0] = qa[0]; ra[1] = qa[1];                                      \
    } while (0)

    // A write: row srow, logical chunk sc -> physical chunk sc^(srow&7)
#define CVT_WRITE_A(buf)                                                   \
    do {                                                                   \
        bf16x8 v;                                                          \
        _Pragma("unroll")                                                  \
        for (int j = 0; j < 4; ++j) {                                      \
            v[j] = (__bf16)ra[0][j]; v[j + 4] = (__bf16)ra[1][j];          \
        }                                                                  \
        *(bf16x8*)&As[buf][srow * BK + ((sc ^ (srow & 7)) << 3)] = v;      \
    } while (0)

    // B: LDS linear dest; global source pre-swizzled; reads swizzle back.
#define DMA_B(kt, buf)                                                     \
    do {                                                                   \
        const size_t k0 = (size_t)(kt) * BK;                               \
        _Pragma("unroll")                                                  \
        for (int qq = 0; qq < 4; ++qq) {                                   \
            const int row = (w << 5) + (qq << 3) + drow_l;                 \
            const __bf16* gp = wbase + (size_t)row * DIN + k0              \
                               + ((dch ^ (row & 7)) << 3);                 \
            __builtin_amdgcn_global_load_lds(                              \
                (gas_void*)gp,                                             \
                (las_void*)&BsF[buf][(w << 11) + (qq << 9)], 16, 0, 0);    \
        }                                                                  \
    } while (0)

#define COMPUTE(buf)                                                       \
    do {                                                                   \
        _Pragma("unroll")                                                  \
        for (int kk = 0; kk < 2; ++kk) {                                   \
            bf16x8 af[4], bfr[4];                                          \
            _Pragma("unroll")                                              \
            for (int mi = 0; mi < 4; ++mi) {                               \
                const int row = wm + mi * 16 + l15;                        \
                const int ch  = ((kk << 2) + q) ^ (row & 7);               \
                af[mi] = *(const bf16x8*)&As[buf][row * BK + (ch << 3)];   \
            }                                                              \
            _Pragma("unroll")                                              \
            for (int ni = 0; ni < 4; ++ni) {                               \
                const int brow = wn + ni * 16 + l15;                       \
                const int ch = ((kk << 2) + q) ^ (brow & 7);               \
                bfr[ni] = *(const bf16x8*)&BsF[buf][brow * BK + (ch << 3)]; \
            }                                                              \
            _Pragma("unroll")                                              \
            for (int mi = 0; mi < 4; ++mi)                                 \
                _Pragma("unroll")                                          \
                for (int ni = 0; ni < 4; ++ni)                             \
                    acc[mi][ni] = __builtin_amdgcn_mfma_f32_16x16x32_bf16( \
                        af[mi], bfr[ni], acc[mi][ni], 0, 0, 0);            \
        }                                                                  \
    } while (0)

    f32x4 acc[4][4];
#pragma unroll
    for (int mi = 0; mi < 4; ++mi)
#pragma unroll
        for (int ni = 0; ni < 4; ++ni) acc[mi][ni] = f32x4{0.f, 0.f, 0.f, 0.f};

    // prologue: A(0) regs + DMA B(0) into buf0; write A(0); prefetch A(1).
    ISSUE_A(0);
    DMA_B(0, 0);
    CVT_WRITE_A(0);      // compiler waits ra(0) (vmcnt(4)): DMA(0) in flight
    ISSUE_A(BK);         // outstanding: DMA(0)[4] + ra(1)[2]

    for (int kt = 0; kt < NT; ++kt) {
        const int cur = kt & 1;
        // Drain DMA(kt): outstanding = DMA(kt)[4 oldest] + ra(kt+1)[2 newer].
        if (kt + 1 < NT)
            asm volatile("s_waitcnt vmcnt(2)" ::: "memory");
        else
            asm volatile("s_waitcnt vmcnt(0)" ::: "memory");  // tail: DMA only
        asm volatile("s_waitcnt lgkmcnt(0)" ::: "memory");
        __builtin_amdgcn_s_barrier();

        // after barrier: all waves done reading buf cur^1 -> WAR-safe refill.
        if (kt + 1 < NT) DMA_B(kt + 1, cur ^ 1);

        COMPUTE(cur);

        if (kt + 1 < NT) {
            CVT_WRITE_A(cur ^ 1);   // drains ra(kt+1), DMA stays in flight
            if (kt + 2 < NT) ISSUE_A((kt + 2) * BK);
        }
    }

    // epilogue: C/D layout col = lane&15, row = (lane>>4)*4 + j (verified R1)
    const int r0 = (lane >> 4) * 4;
    const int c  = lane & 15;
    float bias_n[4];
#pragma unroll
    for (int ni = 0; ni < 4; ++ni)
        bias_n[ni] = Bias[g * DOUT + wn + ni * 16 + c];
#pragma unroll
    for (int mi = 0; mi < 4; ++mi) {
#pragma unroll
        for (int j = 0; j < 4; ++j) {
            const int row = bm0 + wm + mi * 16 + r0 + j;
            float* yrow = Y + (size_t)row * (NGRP * DOUT) + g * DOUT + wn;
#pragma unroll
            for (int ni = 0; ni < 4; ++ni)
                yrow[ni * 16 + c] = acc[mi][ni][j] + bias_n[ni];
        }
    }
#undef ISSUE_A
#undef CVT_WRITE_A
#undef DMA_B
#undef COMPUTE
}

extern "C" void kernel_launch(void* const* d_in, const int* in_sizes, int n_in,
                              void* d_out, int out_size, void* d_ws, size_t ws_size,
                              hipStream_t stream) {
    const float* X    = (const float*)d_in[0];
    const float* W    = (const float*)d_in[1];
    const float* Bias = (const float*)d_in[2];
    float* Y          = (float*)d_out;
    __bf16* Wb        = (__bf16*)d_ws;   // 8 MB scratch

    // prepass: 16*512*512 = 4M elems / (256 thr * 8 elems) = 2048 blocks
    wcvt_kernel<<<2048, 256, 0, stream>>>(W, Wb);

    const int grid = NGRP * (BATCH / BM);  // 16*32 = 512
    MultiLinear_48498770706571_kernel<<<grid, 1024, 0, stream>>>(X, Wb, Bias, Y);
}

// Round 18
// 79.715 us; speedup vs baseline: 1.8018x; 1.8018x over previous
//
#include <hip/hip_runtime.h>
#include <hip/hip_bf16.h>

// MultiLinear: y[b,g,o] = sum_i x[b,g,i] * W[g,o,i] + bias[g,o]
// B=4096, G=16, DIN=512, DOUT=512, fp32 in/out.
// R18 = R15 geometry (best, 72.6us: BM=128 BN=512 BK=64, 8 waves, X read
// once, B bf16-DMA, chunk-XOR conflict-free LDS, XCD swizzle) with the
// CORRECTED m201-style 4-phase schedule (R14 had the vmcnt(0)-per-tile
// defect that m218 quantifies at -38..73%):
//   tile-top: ISSUE_A(kt+1) -> vmcnt(2) [drains DMA_B(kt) ONLY] -> bar
//   P0: {read af0-3(kk0)+bfr(kk0) || DMA_B half1} bar MFMA16 bar
//   P1: {read af4-7(kk0)          || DMA_B half2} bar MFMA16 bar
//   P2: {read af0-3(kk1)+bfr(kk1) || CVT_WRITE_A (vmcnt(4): keeps DMA)} ...
//   P3: {read af4-7(kk1)} bar MFMA16 bar
// vmcnt never 0 in the loop (only final tile). setprio(1) around each MFMA
// quadrant (T5: phases create wave role-diversity).

#define BATCH 4096
#define NGRP  16
#define DIN   512
#define DOUT  512

#define BM 128
#define BN 512
#define BK 64
#define NT (DIN / BK)   // 8 K-tiles

typedef __bf16 bf16x8 __attribute__((ext_vector_type(8)));
typedef float  f32x4  __attribute__((ext_vector_type(4)));
typedef const __attribute__((address_space(1))) void gas_void;
typedef __attribute__((address_space(3))) void las_void;

// ---------- prepass: W fp32 -> bf16 into d_ws ----------
__global__ __launch_bounds__(256)
void wcvt_kernel(const float* __restrict__ W, __bf16* __restrict__ Wb) {
    const int i = (blockIdx.x * 256 + threadIdx.x) * 8;
    f32x4 a = *(const f32x4*)(W + i);
    f32x4 b = *(const f32x4*)(W + i + 4);
    bf16x8 v;
#pragma unroll
    for (int j = 0; j < 4; ++j) { v[j] = (__bf16)a[j]; v[j + 4] = (__bf16)b[j]; }
    *(bf16x8*)(Wb + i) = v;
}

// ---------- main GEMM ----------
__global__ __launch_bounds__(512, 2)
void MultiLinear_48498770706571_kernel(const float* __restrict__ X,
                                       const __bf16* __restrict__ Wb,
                                       const float* __restrict__ Bias,
                                       float* __restrict__ Y) {
    // 512 blocks / 8 XCDs = 64 consecutive tiles (2 full groups) per XCD.
    const int bid = (blockIdx.x & 7) * 64 + (blockIdx.x >> 3);
    const int g   = bid >> 5;          // 32 m-tiles per group, 1 n-tile
    const int mt  = bid & 31;
    const int bm0 = mt * BM;

    __shared__ __bf16 As[2][BM * BK];    // 32 KB: 128B rows, chunk-swz
    __shared__ __bf16 BsF[2][BN * BK];   // 128 KB: linear, DMA, chunk-swz

    const int tid  = threadIdx.x;
    const int lane = tid & 63;
    const int w    = tid >> 6;        // 0..7
    const int wn   = w * 64;          // wave n-offset (wm = 0 for all)
    const int l15  = lane & 15;
    const int q    = lane >> 4;       // 0..3

    // A staging: 4 thr/row, 16 floats each; 128 rows by 512 threads.
    const int srow = tid >> 2;        // 0..127
    const int sc2  = (tid & 3) * 2;   // first 16B-chunk (of 8) this thr writes
    const float* pA = X + (size_t)(bm0 + srow) * (NGRP * DIN) + g * DIN + (tid & 3) * 16;

    // B DMA geometry: per wave 64 rows; 8 issues of 1 KB (8 rows x 128 B),
    // split 4+4 across phases P0/P1.
    const int drow_l = lane >> 3;     // 0..7 row within instr
    const int dch    = lane & 7;      // 16B chunk within row
    const __bf16* wbase = Wb + (size_t)g * (DOUT * DIN);

    f32x4 ra[4];   // 16 VGPRs in flight (A only; B is DMA)

#define ISSUE_A(k0)                                                        \
    do {                                                                   \
        const f32x4* qa = (const f32x4*)(pA + (k0));                       \
        ra[0] = qa[0]; ra[1] = qa[1]; ra[2] = qa[2]; ra[3] = qa[3];        \
    } while (0)

    // A write: row srow, logical chunks sc2,sc2+1 -> physical chunk ^(srow&7)
#define CVT_WRITE_A(buf)                                                   \
    do {                                                                   \
        bf16x8 v0, v1;                                                     \
        _Pragma("unroll")                                                  \
        for (int j = 0; j < 4; ++j) {                                      \
            v0[j] = (__bf16)ra[0][j]; v0[j + 4] = (__bf16)ra[1][j];        \
            v1[j] = (__bf16)ra[2][j]; v1[j + 4] = (__bf16)ra[3][j];        \
        }                                                                  \
        const int s = srow & 7;                                            \
        __bf16* base = &As[buf][srow * BK];                                \
        *(bf16x8*)&base[((sc2 ^ s) << 3)]       = v0;                      \
        *(bf16x8*)&base[(((sc2 + 1) ^ s) << 3)] = v1;                      \
    } while (0)

    // B half-DMA: 4 of the 8 per-wave 1KB instrs (H = 0 or 1).
#define DMA_B_HALF(kt, buf, H)                                             \
    do {                                                                   \
        const size_t k0 = (size_t)(kt) * BK;                               \
        _Pragma("unroll")                                                  \
        for (int qq = (H) * 4; qq < (H) * 4 + 4; ++qq) {                   \
            const int row = (w << 6) + (qq << 3) + drow_l;                 \
            const __bf16* gp = wbase + (size_t)row * DIN + k0              \
                               + ((dch ^ (row & 7)) << 3);                 \
            __builtin_amdgcn_global_load_lds(                              \
                (gas_void*)gp,                                             \
                (las_void*)&BsF[buf][(w << 12) + (qq << 9)], 16, 0, 0);    \
        }                                                                  \
    } while (0)

#define READ_AF(MLO, KK, buf)                                              \
    do {                                                                   \
        _Pragma("unroll")                                                  \
        for (int mi = 0; mi < 4; ++mi) {                                   \
            const int row = ((MLO) + mi) * 16 + l15;                       \
            const int ch  = (((KK) << 2) + q) ^ (row & 7);                 \
            af[mi] = *(const bf16x8*)&As[buf][row * BK + (ch << 3)];       \
        }                                                                  \
    } while (0)

#define READ_BF(KK, buf)                                                   \
    do {                                                                   \
        _Pragma("unroll")                                                  \
        for (int ni = 0; ni < 4; ++ni) {                                   \
            const int brow = wn + ni * 16 + l15;                           \
            const int ch   = (((KK) << 2) + q) ^ (brow & 7);               \
            bfr[ni] = *(const bf16x8*)&BsF[buf][brow * BK + (ch << 3)];    \
        }                                                                  \
    } while (0)

#define MFMA_Q(MLO)                                                        \
    do {                                                                   \
        __builtin_amdgcn_s_setprio(1);                                     \
        _Pragma("unroll")                                                  \
        for (int mi = 0; mi < 4; ++mi)                                     \
            _Pragma("unroll")                                              \
            for (int ni = 0; ni < 4; ++ni)                                 \
                acc[(MLO) + mi][ni] = __builtin_amdgcn_mfma_f32_16x16x32_bf16( \
                    af[mi], bfr[ni], acc[(MLO) + mi][ni], 0, 0, 0);        \
        __builtin_amdgcn_s_setprio(0);                                     \
    } while (0)

#define LGKM0() asm volatile("s_waitcnt lgkmcnt(0)" ::: "memory")
#define BAR()   __builtin_amdgcn_s_barrier()

    f32x4 acc[8][4];
#pragma unroll
    for (int mi = 0; mi < 8; ++mi)
#pragma unroll
        for (int ni = 0; ni < 4; ++ni) acc[mi][ni] = f32x4{0.f, 0.f, 0.f, 0.f};

    // prologue: stage tile 0 into buf 0 (ra(0) drained by CVT; DMA(0) stays)
    ISSUE_A(0);
    DMA_B_HALF(0, 0, 0);
    DMA_B_HALF(0, 0, 1);
    CVT_WRITE_A(0);          // implicit vmcnt(8): waits ra(0), keeps DMA(0)

    for (int kt = 0; kt < NT; ++kt) {
        const int cur = kt & 1;
        const int nxt = cur ^ 1;
        const bool pre = (kt + 1 < NT);
        bf16x8 af[4], bfr[4];

        // ---- tile-top: issue ra(kt+1), then counted drain of DMA_B(kt) ----
        if (pre) {
            ISSUE_A((kt + 1) * BK);
            asm volatile("s_waitcnt vmcnt(4)" ::: "memory");  // keep 4 ra
        } else {
            asm volatile("s_waitcnt vmcnt(0)" ::: "memory");  // final tile
        }
        LGKM0();
        BAR();

        // ---- P0: af(m0-3,kk0) + bfr(kk0); DMA_B(kt+1) half 1 ----
        READ_AF(0, 0, cur);
        READ_BF(0, cur);
        if (pre) DMA_B_HALF(kt + 1, nxt, 0);
        LGKM0(); BAR();
        MFMA_Q(0);
        BAR();

        // ---- P1: af(m4-7,kk0); DMA_B(kt+1) half 2 ----
        READ_AF(4, 0, cur);
        if (pre) DMA_B_HALF(kt + 1, nxt, 1);
        LGKM0(); BAR();
        MFMA_Q(4);
        BAR();

        // ---- P2: af(m0-3,kk1) + bfr(kk1); cvt+write A(kt+1) ----
        READ_AF(0, 1, cur);
        READ_BF(1, cur);
        if (pre) CVT_WRITE_A(nxt);   // implicit vmcnt(8): waits ra, keeps DMA
        LGKM0(); BAR();
        MFMA_Q(0);
        BAR();

        // ---- P3: af(m4-7,kk1) ----
        READ_AF(4, 1, cur);
        LGKM0(); BAR();
        MFMA_Q(4);
        BAR();
    }

    // epilogue: C/D layout col = lane&15, row = (lane>>4)*4 + j (verified R1)
    const int r0 = (lane >> 4) * 4;
    const int c  = lane & 15;
    float bias_n[4];
#pragma unroll
    for (int ni = 0; ni < 4; ++ni)
        bias_n[ni] = Bias[g * DOUT + wn + ni * 16 + c];
#pragma unroll
    for (int mi = 0; mi < 8; ++mi) {
#pragma unroll
        for (int j = 0; j < 4; ++j) {
            const int row = bm0 + mi * 16 + r0 + j;
            float* yrow = Y + (size_t)row * (NGRP * DOUT) + g * DOUT + wn;
#pragma unroll
            for (int ni = 0; ni < 4; ++ni)
                yrow[ni * 16 + c] = acc[mi][ni][j] + bias_n[ni];
        }
    }
#undef ISSUE_A
#undef CVT_WRITE_A
#undef DMA_B_HALF
#undef READ_AF
#undef READ_BF
#undef MFMA_Q
#undef LGKM0
#undef BAR
}

extern "C" void kernel_launch(void* const* d_in, const int* in_sizes, int n_in,
                              void* d_out, int out_size, void* d_ws, size_t ws_size,
                              hipStream_t stream) {
    const float* X    = (const float*)d_in[0];
    const float* W    = (const float*)d_in[1];
    const float* Bias = (const float*)d_in[2];
    float* Y          = (float*)d_out;
    __bf16* Wb        = (__bf16*)d_ws;   // 8 MB scratch

    // prepass: 16*512*512 = 4M elems / (256 thr * 8 elems) = 2048 blocks
    wcvt_kernel<<<2048, 256, 0, stream>>>(W, Wb);

    const int grid = NGRP * (BATCH / BM);  // 16*32 = 512
    MultiLinear_48498770706571_kernel<<<grid, 512, 0, stream>>>(X, Wb, Bias, Y);
}